// Round 4
// baseline (488.578 us; speedup 1.0000x reference)
//
#include <hip/hip_runtime.h>
#include <hip/hip_bf16.h>

typedef __attribute__((ext_vector_type(8))) short short8;   // 8 bf16 (4 VGPRs) — MFMA A/B frag
typedef __attribute__((ext_vector_type(4))) float f32x4;    // MFMA C/D frag

#define DDIM 256
#define WROW 257
#define WSTRIDE 66049  // 257*257

__device__ __forceinline__ unsigned short f2bf(float f) {
    unsigned int u = __float_as_uint(f);
    u += 0x7fff + ((u >> 16) & 1);   // RNE (finite values)
    return (unsigned short)(u >> 16);
}
__device__ __forceinline__ float bf2f(unsigned short s) {
    return __uint_as_float(((unsigned int)s) << 16);
}

// ======================= FAST PATH =======================

// Transpose+convert one 64x64 tile: Wt[n][j][k] = bf16(W[n][k][j]) for j,k<256.
__global__ __launch_bounds__(256) void conv_w_kernel(
    const float* __restrict__ Wf, unsigned short* __restrict__ Wt)
{
    __shared__ float tile[64][65];
    const int tid = threadIdx.x;
    const int n  = blockIdx.y;
    const int tj = (blockIdx.x & 3) * 64;
    const int tk = (blockIdx.x >> 2) * 64;
    const float* Wn = Wf + (size_t)n * WSTRIDE;
    #pragma unroll
    for (int it = 0; it < 16; ++it) {
        int k = it * 4 + (tid >> 6);
        int j = tid & 63;
        tile[k][j] = Wn[(size_t)(tk + k) * WROW + tj + j];   // coalesced along j
    }
    __syncthreads();
    unsigned short* out = Wt + ((size_t)n << 16);
    #pragma unroll
    for (int it = 0; it < 8; ++it) {
        int jr = it * 8 + (tid >> 5);
        int k2 = (tid & 31) * 2;
        unsigned int lo = f2bf(tile[k2][jr]);
        unsigned int hi = f2bf(tile[k2 + 1][jr]);
        *reinterpret_cast<unsigned int*>(out + (size_t)(tj + jr) * 256 + tk + k2) = lo | (hi << 16);
    }
}

// Shared Xe gather: T is [128][256] bf16 tile (linear). Writes per-thread 256B chunk.
__device__ __forceinline__ void xe_gather(const unsigned short* T, unsigned short* Xe,
                                          int bt, int tid) {
    const int lane = tid & 63, wv = tid >> 6, qw = lane >> 4, r15 = lane & 15;
    uint4* xe = reinterpret_cast<uint4*>(Xe + ((size_t)(bt * 256 + tid)) * 128);
    #pragma unroll
    for (int m = 0; m < 8; ++m) {
        unsigned int w[8];
        #pragma unroll
        for (int nf = 0; nf < 4; ++nf) {
            unsigned int lo = T[(m * 16 + qw * 4 + 0) * 256 + wv * 64 + nf * 16 + r15];
            unsigned int l1 = T[(m * 16 + qw * 4 + 1) * 256 + wv * 64 + nf * 16 + r15];
            unsigned int l2 = T[(m * 16 + qw * 4 + 2) * 256 + wv * 64 + nf * 16 + r15];
            unsigned int l3 = T[(m * 16 + qw * 4 + 3) * 256 + wv * 64 + nf * 16 + r15];
            w[nf * 2 + 0] = lo | (l1 << 16);
            w[nf * 2 + 1] = l2 | (l3 << 16);
        }
        xe[m * 2 + 0] = make_uint4(w[0], w[1], w[2], w[3]);
        xe[m * 2 + 1] = make_uint4(w[4], w[5], w[6], w[7]);
    }
}

// Layer-1 input prep: X f32 row-major -> Xbf (bf16 row-major) + Xe (epilogue layout)
__global__ __launch_bounds__(256) void conv_x_rm_kernel(
    const float* __restrict__ X, unsigned short* __restrict__ Xbf, unsigned short* __restrict__ Xe)
{
    __shared__ __align__(16) unsigned short T[128 * 256];
    const int tid = threadIdx.x;
    const int b0 = blockIdx.x * 128;
    const float4* Xv = reinterpret_cast<const float4*>(X + (size_t)b0 * 256);
    uint2* Xo = reinterpret_cast<uint2*>(Xbf + (size_t)b0 * 256);
    #pragma unroll
    for (int it = 0; it < 32; ++it) {
        int idx4 = it * 256 + tid;
        float4 v = Xv[idx4];
        uint2 p;
        p.x = (unsigned)f2bf(v.x) | ((unsigned)f2bf(v.y) << 16);
        p.y = (unsigned)f2bf(v.z) | ((unsigned)f2bf(v.w) << 16);
        *reinterpret_cast<uint2*>(&T[idx4 * 4]) = p;
        Xo[idx4] = p;
    }
    __syncthreads();
    xe_gather(T, Xe, blockIdx.x, tid);
}

// Layer-2/3 input prep: Ht bf16 [256][2048] (k-major) -> Xbf row-major + Xe
__global__ __launch_bounds__(256) void conv_x_tr_kernel(
    const unsigned short* __restrict__ Hsrc, unsigned short* __restrict__ Xbf,
    unsigned short* __restrict__ Xe)
{
    __shared__ __align__(16) unsigned short T[128 * 256];
    const int tid = threadIdx.x;
    const int b0 = blockIdx.x * 128;
    #pragma unroll
    for (int it = 0; it < 64; ++it) {
        int lin = it * 256 + tid;
        int k = lin >> 6, bp = lin & 63;
        unsigned int v = *reinterpret_cast<const unsigned int*>(Hsrc + (size_t)k * 2048 + b0 + bp * 2);
        T[(bp * 2) * 256 + k]     = (unsigned short)(v & 0xffff);
        T[(bp * 2 + 1) * 256 + k] = (unsigned short)(v >> 16);
    }
    __syncthreads();
    uint4* Xo = reinterpret_cast<uint4*>(Xbf + (size_t)b0 * 256);
    #pragma unroll
    for (int it = 0; it < 16; ++it) {   // 4096 uint4 per 128x256 tile (BUGFIX: was 32 -> OOB)
        int idx8 = it * 256 + tid;
        Xo[idx8] = *reinterpret_cast<uint4*>(&T[idx8 * 8]);
    }
    xe_gather(T, Xe, blockIdx.x, tid);
}

// Layer: Ht[n][b] = bf16( x_b^T A_n x_b + v_n.x_b + d_n ).
// BM=128 rows/block, 4 waves (wave = j-band of 64). Single barrier; B 2-deep reg prefetch.
__global__ __launch_bounds__(256, 2) void pn3_kernel(
    const unsigned short* __restrict__ Xbf,  // [2048][256] bf16 row-major
    const unsigned short* __restrict__ Xe,   // epilogue-layout bf16
    const unsigned short* __restrict__ Wt,   // [256][256][256] bf16 (j-major)
    const float* __restrict__ Wf,            // original W f32 (for v, d)
    unsigned short* __restrict__ Ht)         // [256][2048] bf16
{
    __shared__ __align__(16) char Xl[65536];  // bf16 [128][256], XOR-swizzled

    const int tid  = threadIdx.x;
    const int lane = tid & 63;
    const int wv   = tid >> 6;
    const int qw   = lane >> 4;
    const int r15  = lane & 15;

    // XCD swizzle: 16 row-tiles of one n -> same XCD back-to-back.
    const int fid = blockIdx.y * 16 + blockIdx.x;
    const int t   = fid >> 3;
    const int bt  = t & 15;
    const int n   = (fid & 7) + 8 * (t >> 4);
    const int b0  = bt * 128;

    // ---- stage bf16 X tile (64 KB) with write-side XOR swizzle ----
    {
        const uint4* xs = reinterpret_cast<const uint4*>(Xbf + (size_t)b0 * 256);
        #pragma unroll
        for (int c = 0; c < 16; ++c) {
            uint4 v = xs[c * 256 + tid];
            int L = c * 4096 + tid * 16;
            int d = L ^ (((L >> 9) & 7) << 4);
            *reinterpret_cast<uint4*>(&Xl[d]) = v;
        }
    }

    // ---- acc init = v_n[j] broadcast over rows ----
    const float* Wfn = Wf + (size_t)n * WSTRIDE;
    f32x4 acc[8][4];
    #pragma unroll
    for (int nf = 0; nf < 4; ++nf) {
        int j = wv * 64 + nf * 16 + r15;
        float vj = Wfn[(size_t)j * WROW + 256] + Wfn[65792 + j];
        #pragma unroll
        for (int m = 0; m < 8; ++m) acc[m][nf] = f32x4{vj, vj, vj, vj};
    }

    // ---- B prefetch: kk=0,1 into bb[0],bb[1] ----
    const unsigned short* Wn = Wt + ((size_t)n << 16);
    short8 bb[3][4];
    #pragma unroll
    for (int p = 0; p < 2; ++p)
        #pragma unroll
        for (int nf = 0; nf < 4; ++nf) {
            int j = wv * 64 + nf * 16 + r15;
            bb[p][nf] = *reinterpret_cast<const short8*>(Wn + (size_t)j * 256 + p * 32 + qw * 8);
        }

    __syncthreads();   // X tile ready; only barrier before the reduce

    // ---- K loop: 8 steps of K=32, no barriers, 2-deep B prefetch ----
    #pragma unroll
    for (int kk = 0; kk < 8; ++kk) {
        if (kk < 6) {
            #pragma unroll
            for (int nf = 0; nf < 4; ++nf) {
                int j = wv * 64 + nf * 16 + r15;
                bb[(kk + 2) % 3][nf] =
                    *reinterpret_cast<const short8*>(Wn + (size_t)j * 256 + (kk + 2) * 32 + qw * 8);
            }
        }
        #pragma unroll
        for (int m = 0; m < 8; ++m) {
            int row = m * 16 + r15;
            int byte = (row * 512 + kk * 64 + qw * 16) ^ ((row & 7) << 4);
            short8 a = *reinterpret_cast<short8*>(&Xl[byte]);
            #pragma unroll
            for (int nf = 0; nf < 4; ++nf)
                acc[m][nf] = __builtin_amdgcn_mfma_f32_16x16x32_bf16(a, bb[kk % 3][nf], acc[m][nf], 0, 0, 0);
        }
    }

    // ---- epilogue: ps = sum_j C*x from pre-permuted Xe (16 x 16B coalesced loads) ----
    const short8* xev = reinterpret_cast<const short8*>(Xe + ((size_t)(bt * 256 + tid)) * 128);
    float ps[8][4];
    #pragma unroll
    for (int m = 0; m < 8; ++m)
        #pragma unroll
        for (int r = 0; r < 4; ++r) ps[m][r] = 0.f;
    #pragma unroll
    for (int m = 0; m < 8; ++m) {
        #pragma unroll
        for (int h = 0; h < 2; ++h) {
            short8 e = xev[m * 2 + h];
            #pragma unroll
            for (int n2 = 0; n2 < 2; ++n2) {
                int nf = h * 2 + n2;
                #pragma unroll
                for (int r = 0; r < 4; ++r)
                    ps[m][r] += acc[m][nf][r] * bf2f((unsigned short)e[n2 * 4 + r]);
            }
        }
    }
    #pragma unroll
    for (int off = 1; off <= 8; off <<= 1)
        #pragma unroll
        for (int m = 0; m < 8; ++m)
            #pragma unroll
            for (int r = 0; r < 4; ++r) ps[m][r] += __shfl_xor(ps[m][r], off, 64);

    __syncthreads();                     // Xl reads done -> reuse as reduce buffer
    float* red = reinterpret_cast<float*>(Xl);
    if (r15 == 0) {
        #pragma unroll
        for (int m = 0; m < 8; ++m)
            #pragma unroll
            for (int r = 0; r < 4; ++r)
                red[wv * 128 + m * 16 + qw * 4 + r] = ps[m][r];
    }
    __syncthreads();
    if (tid < 128) {
        float s = red[tid] + red[128 + tid] + red[256 + tid] + red[384 + tid] + Wfn[66048];
        Ht[(size_t)n * 2048 + b0 + tid] = f2bf(s);
    }
}

__global__ __launch_bounds__(256) void out_tr_kernel(
    const unsigned short* __restrict__ H3, const float* __restrict__ w_out,
    const float* __restrict__ b_out, float* __restrict__ out)
{
    __shared__ float red2[256];
    const int tid = threadIdx.x;
    const int b = blockIdx.x * 128 + (tid & 127);
    const int half = tid >> 7;
    float s = 0.f;
    #pragma unroll 8
    for (int k = 0; k < 128; ++k) {
        int nn = half * 128 + k;
        s += bf2f(H3[(size_t)nn * 2048 + b]) * w_out[nn];
    }
    red2[tid] = s;
    __syncthreads();
    if (tid < 128) out[b] = red2[tid] + red2[tid + 128] + b_out[0];
}

// ======================= FALLBACK PATH (small ws) =======================

__global__ __launch_bounds__(256, 2) void pn_layer_kernel(
    const float* __restrict__ X, const float* __restrict__ W, float* __restrict__ H)
{
    __shared__ __align__(16) char Xl[64 * 256 * 2];
    __shared__ __align__(16) char Wl[2][256 * 32 * 2];
    const int tid  = threadIdx.x;
    const int lane = tid & 63;
    const int wv   = tid >> 6;
    const int qw   = lane >> 4;
    const int r15  = lane & 15;
    const int n  = blockIdx.y;
    const int b0 = blockIdx.x * 64;
    const float* Wn = W + (size_t)n * WSTRIDE;
    {
        const float4* Xv = reinterpret_cast<const float4*>(X + (size_t)b0 * DDIM);
        #pragma unroll
        for (int it = 0; it < 16; ++it) {
            int idx4 = tid + it * 256;
            int r = idx4 >> 6, c4 = idx4 & 63;
            float4 v = Xv[r * 64 + c4];
            uint2 p;
            p.x = (unsigned)f2bf(v.x) | ((unsigned)f2bf(v.y) << 16);
            p.y = (unsigned)f2bf(v.z) | ((unsigned)f2bf(v.w) << 16);
            int byte = (r * 512 + c4 * 8) ^ ((r & 7) << 4);
            *reinterpret_cast<uint2*>(&Xl[byte]) = p;
        }
    }
    f32x4 acc[4][4];
    #pragma unroll
    for (int nf = 0; nf < 4; ++nf) {
        int j = wv * 64 + nf * 16 + r15;
        float vj = Wn[(size_t)j * WROW + 256] + Wn[65792 + j];
        #pragma unroll
        for (int m = 0; m < 4; ++m) acc[m][nf] = f32x4{vj, vj, vj, vj};
    }
    auto stageW = [&](int buf, int kk) {
        const int k0 = kk * 32;
        const int j  = tid;
        float t[32];
        #pragma unroll
        for (int k = 0; k < 32; ++k) t[k] = Wn[(size_t)(k0 + k) * WROW + j];
        char* Wb = Wl[buf];
        #pragma unroll
        for (int g = 0; g < 4; ++g) {
            unsigned int p0 = (unsigned)f2bf(t[g*8+0]) | ((unsigned)f2bf(t[g*8+1]) << 16);
            unsigned int p1 = (unsigned)f2bf(t[g*8+2]) | ((unsigned)f2bf(t[g*8+3]) << 16);
            unsigned int p2 = (unsigned)f2bf(t[g*8+4]) | ((unsigned)f2bf(t[g*8+5]) << 16);
            unsigned int p3 = (unsigned)f2bf(t[g*8+6]) | ((unsigned)f2bf(t[g*8+7]) << 16);
            int byte = (j * 64 + g * 16) ^ ((j & 7) << 4);
            *reinterpret_cast<uint4*>(&Wb[byte]) = make_uint4(p0, p1, p2, p3);
        }
    };
    auto computeK = [&](int buf, int kk) {
        char* Wb = Wl[buf];
        short8 a[4], bbf[4];
        #pragma unroll
        for (int m = 0; m < 4; ++m) {
            int row = m * 16 + r15;
            int byte = (row * 512 + kk * 64 + qw * 16) ^ ((row & 7) << 4);
            a[m] = *reinterpret_cast<short8*>(&Xl[byte]);
        }
        #pragma unroll
        for (int nf = 0; nf < 4; ++nf) {
            int j = wv * 64 + nf * 16 + r15;
            int byte = (j * 64 + qw * 16) ^ ((j & 7) << 4);
            bbf[nf] = *reinterpret_cast<short8*>(&Wb[byte]);
        }
        #pragma unroll
        for (int m = 0; m < 4; ++m)
            #pragma unroll
            for (int nf = 0; nf < 4; ++nf)
                acc[m][nf] = __builtin_amdgcn_mfma_f32_16x16x32_bf16(a[m], bbf[nf], acc[m][nf], 0, 0, 0);
    };
    stageW(0, 0);
    int cur = 0;
    #pragma unroll
    for (int kk = 0; kk < 8; ++kk) {
        __syncthreads();
        if (kk < 7) stageW(cur ^ 1, kk + 1);
        computeK(cur, kk);
        cur ^= 1;
    }
    float ps[16];
    #pragma unroll
    for (int i = 0; i < 16; ++i) ps[i] = 0.f;
    #pragma unroll
    for (int m = 0; m < 4; ++m)
        #pragma unroll
        for (int nf = 0; nf < 4; ++nf) {
            int j = wv * 64 + nf * 16 + r15;
            #pragma unroll
            for (int r = 0; r < 4; ++r) {
                int brow = m * 16 + qw * 4 + r;
                int byte = (brow * 512 + j * 2) ^ ((brow & 7) << 4);
                float xv = bf2f(*reinterpret_cast<unsigned short*>(&Xl[byte]));
                ps[m * 4 + r] += acc[m][nf][r] * xv;
            }
        }
    #pragma unroll
    for (int off = 1; off <= 8; off <<= 1)
        #pragma unroll
        for (int i = 0; i < 16; ++i) ps[i] += __shfl_xor(ps[i], off, 64);
    __syncthreads();
    float* red = reinterpret_cast<float*>(Wl);
    if (r15 == 0) {
        #pragma unroll
        for (int m = 0; m < 4; ++m)
            #pragma unroll
            for (int r = 0; r < 4; ++r)
                red[wv * 64 + m * 16 + qw * 4 + r] = ps[m * 4 + r];
    }
    __syncthreads();
    if (tid < 64) {
        float s = red[tid] + red[64 + tid] + red[128 + tid] + red[192 + tid] + Wn[66048];
        H[(size_t)(b0 + tid) * DDIM + n] = s;
    }
}

__global__ __launch_bounds__(256) void out_kernel(
    const float* __restrict__ H, const float* __restrict__ w_out,
    const float* __restrict__ b_out, float* __restrict__ out)
{
    int b = blockIdx.x * 4 + (threadIdx.x >> 6);
    int lane = threadIdx.x & 63;
    const float* h = H + (size_t)b * 256;
    float s = 0.f;
    #pragma unroll
    for (int c = 0; c < 4; ++c) s += h[lane + c * 64] * w_out[lane + c * 64];
    #pragma unroll
    for (int off = 1; off < 64; off <<= 1) s += __shfl_xor(s, off, 64);
    if (lane == 0) out[b] = s + b_out[0];
}

extern "C" void kernel_launch(void* const* d_in, const int* in_sizes, int n_in,
                              void* d_out, int out_size, void* d_ws, size_t ws_size,
                              hipStream_t stream) {
    const float* x    = (const float*)d_in[0];
    const float* W1   = (const float*)d_in[1];
    const float* W2   = (const float*)d_in[2];
    const float* W3   = (const float*)d_in[3];
    const float* wout = (const float*)d_in[4];
    const float* bout = (const float*)d_in[5];
    float* out = (float*)d_out;

    const size_t WT_BYTES = (size_t)256 * 256 * 256 * 2;   // 33.55 MB
    const size_t XB_BYTES = (size_t)2048 * 256 * 2;        // 1 MB
    const size_t XE_BYTES = (size_t)2048 * 256 * 2;        // 1 MB
    const size_t HT_BYTES = (size_t)256 * 2048 * 2;        // 1 MB (bf16, transposed)
    const size_t need = WT_BYTES + XB_BYTES + XE_BYTES + 2 * HT_BYTES;  // 37.75 MB

    dim3 blk(256, 1, 1);

    if (ws_size >= need) {
        unsigned short* Wt  = (unsigned short*)d_ws;
        unsigned short* Xbf = (unsigned short*)((char*)d_ws + WT_BYTES);
        unsigned short* Xe  = (unsigned short*)((char*)d_ws + WT_BYTES + XB_BYTES);
        unsigned short* Ht1 = (unsigned short*)((char*)d_ws + WT_BYTES + XB_BYTES + XE_BYTES);
        unsigned short* Ht2 = Ht1 + 256 * 2048;

        const float* Ws[3] = {W1, W2, W3};
        unsigned short* Hout[3] = {Ht1, Ht2, Ht1};

        dim3 cgrid(16, 256), lgrid(16, 256), xgrid(16);
        for (int L = 0; L < 3; ++L) {
            if (L == 0) conv_x_rm_kernel<<<xgrid, blk, 0, stream>>>(x, Xbf, Xe);
            else        conv_x_tr_kernel<<<xgrid, blk, 0, stream>>>(Hout[L - 1], Xbf, Xe);
            conv_w_kernel<<<cgrid, blk, 0, stream>>>(Ws[L], Wt);
            pn3_kernel<<<lgrid, blk, 0, stream>>>(Xbf, Xe, Wt, Ws[L], Hout[L]);
        }
        out_tr_kernel<<<xgrid, blk, 0, stream>>>(Ht1, wout, bout, out);
    } else {
        float* h1 = (float*)d_ws;
        float* h2 = h1 + 2048 * 256;
        dim3 grid(32, 256);
        pn_layer_kernel<<<grid, blk, 0, stream>>>(x,  W1, h1);
        pn_layer_kernel<<<grid, blk, 0, stream>>>(h1, W2, h2);
        pn_layer_kernel<<<grid, blk, 0, stream>>>(h2, W3, h1);
        out_kernel<<<512, blk, 0, stream>>>(h1, wout, bout, out);
    }
}

// Round 5
// 436.526 us; speedup vs baseline: 1.1192x; 1.1192x over previous
//
#include <hip/hip_runtime.h>
#include <hip/hip_bf16.h>

typedef __attribute__((ext_vector_type(8))) short short8;   // 8 bf16 (4 VGPRs) — MFMA A/B frag
typedef __attribute__((ext_vector_type(4))) float f32x4;    // MFMA C/D frag

#define DDIM 256
#define WROW 257
#define WSTRIDE 66049  // 257*257

__device__ __forceinline__ unsigned short f2bf(float f) {
    unsigned int u = __float_as_uint(f);
    u += 0x7fff + ((u >> 16) & 1);   // RNE (finite values)
    return (unsigned short)(u >> 16);
}
__device__ __forceinline__ float bf2f(unsigned short s) {
    return __uint_as_float(((unsigned int)s) << 16);
}

// ======================= FAST PATH =======================

// Symmetrized, pre-scaled, transposed W:
//   Wt2[n][j][k] = s * (A[k][j] + A[j][k]),  s = 1 for ktile<jtile, 0.5 for ktile==jtile (32-granular)
//   (region ktile>jtile never written, never read)
// One block per (n, 64x64 tile-pair (tk<=tj)).
__global__ __launch_bounds__(256) void conv_w2_kernel(
    const float* __restrict__ Wf, unsigned short* __restrict__ Wt2)
{
    __shared__ float tKJ[64][65];   // A[tk*64+k][tj*64+j]
    __shared__ float tJK[64][65];   // A[tj*64+k][tk*64+j]
    const int TJ[10] = {0,1,1,2,2,2,3,3,3,3};
    const int TK[10] = {0,0,1,0,1,2,0,1,2,3};
    const int tid = threadIdx.x;
    const int n   = blockIdx.y;
    const int tj  = TJ[blockIdx.x];
    const int tk  = TK[blockIdx.x];
    const float* Wn = Wf + (size_t)n * WSTRIDE;
    #pragma unroll
    for (int it = 0; it < 16; ++it) {
        int r = it * 4 + (tid >> 6);
        int c = tid & 63;
        tKJ[r][c] = Wn[(size_t)(tk * 64 + r) * WROW + tj * 64 + c];
        tJK[r][c] = Wn[(size_t)(tj * 64 + r) * WROW + tk * 64 + c];
    }
    __syncthreads();
    unsigned short* out = Wt2 + ((size_t)n << 16);
    #pragma unroll
    for (int it = 0; it < 8; ++it) {
        int jl = it * 8 + (tid >> 5);            // j-local 0..63
        int k2 = (tid & 31) * 2;                 // k-local 0..62 (pair)
        int p32 = tk * 2 + (k2 >> 5);
        int q32 = tj * 2 + (jl >> 5);
        if (p32 <= q32) {
            float sc = (p32 == q32) ? 0.5f : 1.0f;
            float v0 = sc * (tKJ[k2][jl]     + tJK[jl][k2]);
            float v1 = sc * (tKJ[k2 + 1][jl] + tJK[jl][k2 + 1]);
            unsigned int u = (unsigned)f2bf(v0) | ((unsigned)f2bf(v1) << 16);
            *reinterpret_cast<unsigned int*>(out + (size_t)(tj * 64 + jl) * 256 + tk * 64 + k2) = u;
        }
    }
}

// Xe gather for the q-paired 4-wave BM=64 kernel. T = [128][256] bf16 (linear, block-local rows).
// pn-thread (bt, tid): wave wv=tid>>6 owns j-tiles {wv, 7-wv}; 64 shorts per thread:
//   [m(4)][e0: {j=qa*32+r15, r0..3},{j=qa*32+16+r15, r0..3}][e1: same for qb]
__device__ __forceinline__ void xe_gather2(const unsigned short* T, unsigned short* Xe,
                                           int bx, int tid) {
    const int lane = tid & 63, wv = tid >> 6, qw = lane >> 4, r15 = lane & 15;
    const int qa = wv, qb = 7 - wv;
    #pragma unroll
    for (int h = 0; h < 2; ++h) {
        const int bt = bx * 2 + h;
        uint4* xe = reinterpret_cast<uint4*>(Xe + ((size_t)(bt * 256 + tid)) * 64);
        #pragma unroll
        for (int m = 0; m < 4; ++m) {
            const int rbase = h * 64 + m * 16 + qw * 4;
            unsigned int w[8];
            #pragma unroll
            for (int half = 0; half < 2; ++half) {
                int jb = (half == 0 ? qa : qb) * 32 + r15;
                unsigned int a0 = T[(rbase + 0) * 256 + jb];
                unsigned int a1 = T[(rbase + 1) * 256 + jb];
                unsigned int a2 = T[(rbase + 2) * 256 + jb];
                unsigned int a3 = T[(rbase + 3) * 256 + jb];
                unsigned int b0 = T[(rbase + 0) * 256 + jb + 16];
                unsigned int b1 = T[(rbase + 1) * 256 + jb + 16];
                unsigned int b2 = T[(rbase + 2) * 256 + jb + 16];
                unsigned int b3 = T[(rbase + 3) * 256 + jb + 16];
                w[half * 4 + 0] = a0 | (a1 << 16);
                w[half * 4 + 1] = a2 | (a3 << 16);
                w[half * 4 + 2] = b0 | (b1 << 16);
                w[half * 4 + 3] = b2 | (b3 << 16);
            }
            xe[m * 2 + 0] = make_uint4(w[0], w[1], w[2], w[3]);
            xe[m * 2 + 1] = make_uint4(w[4], w[5], w[6], w[7]);
        }
    }
}

// Layer-1 input prep: X f32 row-major -> Xbf (bf16 row-major) + Xe
__global__ __launch_bounds__(256) void conv_x_rm_kernel(
    const float* __restrict__ X, unsigned short* __restrict__ Xbf, unsigned short* __restrict__ Xe)
{
    __shared__ __align__(16) unsigned short T[128 * 256];
    const int tid = threadIdx.x;
    const int b0 = blockIdx.x * 128;
    const float4* Xv = reinterpret_cast<const float4*>(X + (size_t)b0 * 256);
    uint2* Xo = reinterpret_cast<uint2*>(Xbf + (size_t)b0 * 256);
    #pragma unroll
    for (int it = 0; it < 32; ++it) {
        int idx4 = it * 256 + tid;
        float4 v = Xv[idx4];
        uint2 p;
        p.x = (unsigned)f2bf(v.x) | ((unsigned)f2bf(v.y) << 16);
        p.y = (unsigned)f2bf(v.z) | ((unsigned)f2bf(v.w) << 16);
        *reinterpret_cast<uint2*>(&T[idx4 * 4]) = p;
        Xo[idx4] = p;
    }
    __syncthreads();
    xe_gather2(T, Xe, blockIdx.x, tid);
}

// Layer-2/3 input prep: Ht bf16 [256][2048] (k-major) -> Xbf row-major + Xe
__global__ __launch_bounds__(256) void conv_x_tr_kernel(
    const unsigned short* __restrict__ Hsrc, unsigned short* __restrict__ Xbf,
    unsigned short* __restrict__ Xe)
{
    __shared__ __align__(16) unsigned short T[128 * 256];
    const int tid = threadIdx.x;
    const int b0 = blockIdx.x * 128;
    #pragma unroll
    for (int it = 0; it < 64; ++it) {
        int lin = it * 256 + tid;
        int k = lin >> 6, bp = lin & 63;
        unsigned int v = *reinterpret_cast<const unsigned int*>(Hsrc + (size_t)k * 2048 + b0 + bp * 2);
        T[(bp * 2) * 256 + k]     = (unsigned short)(v & 0xffff);
        T[(bp * 2 + 1) * 256 + k] = (unsigned short)(v >> 16);
    }
    __syncthreads();
    uint4* Xo = reinterpret_cast<uint4*>(Xbf + (size_t)b0 * 256);
    #pragma unroll
    for (int it = 0; it < 16; ++it) {   // 4096 uint4 per 128x256 tile
        int idx8 = it * 256 + tid;
        Xo[idx8] = *reinterpret_cast<uint4*>(&T[idx8 * 8]);
    }
    xe_gather2(T, Xe, blockIdx.x, tid);
}

// Symmetric-triangle layer: Ht[n][b] = bf16( x^T S_n x + v_n.x + d_n ).
// BM=64, 4 waves; wave wv owns j-tiles {wv, 7-wv} (q-paired: 9 K-steps every wave).
__global__ __launch_bounds__(256, 3) void pn4_kernel(
    const unsigned short* __restrict__ Xbf,  // [2048][256] bf16 row-major
    const unsigned short* __restrict__ Xe,   // epilogue-layout bf16
    const unsigned short* __restrict__ Wt2,  // [256][256][256] bf16 symmetric-scaled, j-major
    const float* __restrict__ Wf,            // original W f32 (for v, d)
    unsigned short* __restrict__ Ht)         // [256][2048] bf16
{
    __shared__ __align__(16) char Xl[32768];  // bf16 [64][256], XOR-swizzled

    const int tid  = threadIdx.x;
    const int lane = tid & 63;
    const int wv   = tid >> 6;
    const int qw   = lane >> 4;
    const int r15  = lane & 15;
    const int qa   = wv;
    const int qb   = 7 - wv;

    // XCD swizzle: 32 consecutive fids (bt 0..31) share one n; n grouped mod 8 per XCD.
    const int fid = blockIdx.y * 32 + blockIdx.x;
    const int bt  = (fid >> 3) & 31;
    const int n   = (fid & 7) + ((fid >> 8) << 3);
    const int b0  = bt * 64;

    // ---- stage bf16 X tile (32 KB) with write-side XOR swizzle ----
    {
        const uint4* xs = reinterpret_cast<const uint4*>(Xbf + (size_t)b0 * 256);
        #pragma unroll
        for (int c = 0; c < 8; ++c) {
            int idx = c * 256 + tid;
            uint4 v = xs[idx];
            int L = idx * 16;
            int d = L ^ (((L >> 9) & 7) << 4);
            *reinterpret_cast<uint4*>(&Xl[d]) = v;
        }
    }

    // ---- acc init = v_n[j] broadcast over rows ----
    const float* Wfn = Wf + (size_t)n * WSTRIDE;
    const int j0 = qa * 32 + r15, j1 = j0 + 16;
    const int j2 = qb * 32 + r15, j3 = j2 + 16;
    f32x4 acc[4][4];
    {
        float v0 = Wfn[(size_t)j0 * WROW + 256] + Wfn[65792 + j0];
        float v1 = Wfn[(size_t)j1 * WROW + 256] + Wfn[65792 + j1];
        float v2 = Wfn[(size_t)j2 * WROW + 256] + Wfn[65792 + j2];
        float v3 = Wfn[(size_t)j3 * WROW + 256] + Wfn[65792 + j3];
        #pragma unroll
        for (int m = 0; m < 4; ++m) {
            acc[m][0] = f32x4{v0, v0, v0, v0};
            acc[m][1] = f32x4{v1, v1, v1, v1};
            acc[m][2] = f32x4{v2, v2, v2, v2};
            acc[m][3] = f32x4{v3, v3, v3, v3};
        }
    }

    // ---- B row pointers + first-step prefetch (both tiles, before barrier) ----
    const unsigned short* Wn = Wt2 + ((size_t)n << 16);
    const unsigned short* pA0 = Wn + (size_t)j0 * 256 + qw * 8;
    const unsigned short* pA1 = Wn + (size_t)j1 * 256 + qw * 8;
    const unsigned short* pB0 = Wn + (size_t)j2 * 256 + qw * 8;
    const unsigned short* pB1 = Wn + (size_t)j3 * 256 + qw * 8;
    short8 cA0 = *reinterpret_cast<const short8*>(pA0);
    short8 cA1 = *reinterpret_cast<const short8*>(pA1);
    short8 cB0 = *reinterpret_cast<const short8*>(pB0);
    short8 cB1 = *reinterpret_cast<const short8*>(pB1);

    __syncthreads();

    // ---- tile qa: kk = 0..qa (qa+1 steps) ----
    for (int kk = 0; kk <= qa; ++kk) {
        short8 n0, n1;
        const bool more = kk < qa;
        if (more) {
            n0 = *reinterpret_cast<const short8*>(pA0 + (kk + 1) * 32);
            n1 = *reinterpret_cast<const short8*>(pA1 + (kk + 1) * 32);
        }
        #pragma unroll
        for (int m = 0; m < 4; ++m) {
            const int row = m * 16 + r15;
            const int byte = (row * 512 + kk * 64 + qw * 16) ^ ((row & 7) << 4);
            short8 a = *reinterpret_cast<const short8*>(&Xl[byte]);
            acc[m][0] = __builtin_amdgcn_mfma_f32_16x16x32_bf16(a, cA0, acc[m][0], 0, 0, 0);
            acc[m][1] = __builtin_amdgcn_mfma_f32_16x16x32_bf16(a, cA1, acc[m][1], 0, 0, 0);
        }
        if (more) { cA0 = n0; cA1 = n1; }
    }
    // ---- tile qb: kk = 0..qb (qb+1 steps) ----
    for (int kk = 0; kk <= qb; ++kk) {
        short8 n0, n1;
        const bool more = kk < qb;
        if (more) {
            n0 = *reinterpret_cast<const short8*>(pB0 + (kk + 1) * 32);
            n1 = *reinterpret_cast<const short8*>(pB1 + (kk + 1) * 32);
        }
        #pragma unroll
        for (int m = 0; m < 4; ++m) {
            const int row = m * 16 + r15;
            const int byte = (row * 512 + kk * 64 + qw * 16) ^ ((row & 7) << 4);
            short8 a = *reinterpret_cast<const short8*>(&Xl[byte]);
            acc[m][2] = __builtin_amdgcn_mfma_f32_16x16x32_bf16(a, cB0, acc[m][2], 0, 0, 0);
            acc[m][3] = __builtin_amdgcn_mfma_f32_16x16x32_bf16(a, cB1, acc[m][3], 0, 0, 0);
        }
        if (more) { cB0 = n0; cB1 = n1; }
    }

    // ---- epilogue: ps = sum_j D[b,j]*x[b,j] from pre-permuted Xe ----
    float ps[4][4];
    const short8* xev = reinterpret_cast<const short8*>(Xe + ((size_t)(bt * 256 + tid)) * 64);
    #pragma unroll
    for (int m = 0; m < 4; ++m) {
        short8 e0 = xev[m * 2], e1 = xev[m * 2 + 1];
        #pragma unroll
        for (int r = 0; r < 4; ++r) {
            ps[m][r] = acc[m][0][r] * bf2f((unsigned short)e0[r])
                     + acc[m][1][r] * bf2f((unsigned short)e0[4 + r])
                     + acc[m][2][r] * bf2f((unsigned short)e1[r])
                     + acc[m][3][r] * bf2f((unsigned short)e1[4 + r]);
        }
    }
    #pragma unroll
    for (int off = 1; off <= 8; off <<= 1)
        #pragma unroll
        for (int m = 0; m < 4; ++m)
            #pragma unroll
            for (int r = 0; r < 4; ++r) ps[m][r] += __shfl_xor(ps[m][r], off, 64);

    __syncthreads();                     // Xl reads done -> reuse as reduce buffer
    float* red = reinterpret_cast<float*>(Xl);
    if (r15 == 0) {
        #pragma unroll
        for (int m = 0; m < 4; ++m)
            #pragma unroll
            for (int r = 0; r < 4; ++r)
                red[wv * 64 + m * 16 + qw * 4 + r] = ps[m][r];
    }
    __syncthreads();
    if (tid < 64) {
        float s = red[tid] + red[64 + tid] + red[128 + tid] + red[192 + tid] + Wfn[66048];
        Ht[(size_t)n * 2048 + b0 + tid] = f2bf(s);
    }
}

__global__ __launch_bounds__(256) void out_tr_kernel(
    const unsigned short* __restrict__ H3, const float* __restrict__ w_out,
    const float* __restrict__ b_out, float* __restrict__ out)
{
    __shared__ float red2[256];
    const int tid = threadIdx.x;
    const int b = blockIdx.x * 128 + (tid & 127);
    const int half = tid >> 7;
    float s = 0.f;
    #pragma unroll 8
    for (int k = 0; k < 128; ++k) {
        int nn = half * 128 + k;
        s += bf2f(H3[(size_t)nn * 2048 + b]) * w_out[nn];
    }
    red2[tid] = s;
    __syncthreads();
    if (tid < 128) out[b] = red2[tid] + red2[tid + 128] + b_out[0];
}

// ======================= FALLBACK PATH (small ws) =======================

__global__ __launch_bounds__(256, 2) void pn_layer_kernel(
    const float* __restrict__ X, const float* __restrict__ W, float* __restrict__ H)
{
    __shared__ __align__(16) char Xl[64 * 256 * 2];
    __shared__ __align__(16) char Wl[2][256 * 32 * 2];
    const int tid  = threadIdx.x;
    const int lane = tid & 63;
    const int wv   = tid >> 6;
    const int qw   = lane >> 4;
    const int r15  = lane & 15;
    const int n  = blockIdx.y;
    const int b0 = blockIdx.x * 64;
    const float* Wn = W + (size_t)n * WSTRIDE;
    {
        const float4* Xv = reinterpret_cast<const float4*>(X + (size_t)b0 * DDIM);
        #pragma unroll
        for (int it = 0; it < 16; ++it) {
            int idx4 = tid + it * 256;
            int r = idx4 >> 6, c4 = idx4 & 63;
            float4 v = Xv[r * 64 + c4];
            uint2 p;
            p.x = (unsigned)f2bf(v.x) | ((unsigned)f2bf(v.y) << 16);
            p.y = (unsigned)f2bf(v.z) | ((unsigned)f2bf(v.w) << 16);
            int byte = (r * 512 + c4 * 8) ^ ((r & 7) << 4);
            *reinterpret_cast<uint2*>(&Xl[byte]) = p;
        }
    }
    f32x4 acc[4][4];
    #pragma unroll
    for (int nf = 0; nf < 4; ++nf) {
        int j = wv * 64 + nf * 16 + r15;
        float vj = Wn[(size_t)j * WROW + 256] + Wn[65792 + j];
        #pragma unroll
        for (int m = 0; m < 4; ++m) acc[m][nf] = f32x4{vj, vj, vj, vj};
    }
    auto stageW = [&](int buf, int kk) {
        const int k0 = kk * 32;
        const int j  = tid;
        float t[32];
        #pragma unroll
        for (int k = 0; k < 32; ++k) t[k] = Wn[(size_t)(k0 + k) * WROW + j];
        char* Wb = Wl[buf];
        #pragma unroll
        for (int g = 0; g < 4; ++g) {
            unsigned int p0 = (unsigned)f2bf(t[g*8+0]) | ((unsigned)f2bf(t[g*8+1]) << 16);
            unsigned int p1 = (unsigned)f2bf(t[g*8+2]) | ((unsigned)f2bf(t[g*8+3]) << 16);
            unsigned int p2 = (unsigned)f2bf(t[g*8+4]) | ((unsigned)f2bf(t[g*8+5]) << 16);
            unsigned int p3 = (unsigned)f2bf(t[g*8+6]) | ((unsigned)f2bf(t[g*8+7]) << 16);
            int byte = (j * 64 + g * 16) ^ ((j & 7) << 4);
            *reinterpret_cast<uint4*>(&Wb[byte]) = make_uint4(p0, p1, p2, p3);
        }
    };
    auto computeK = [&](int buf, int kk) {
        char* Wb = Wl[buf];
        short8 a[4], bbf[4];
        #pragma unroll
        for (int m = 0; m < 4; ++m) {
            int row = m * 16 + r15;
            int byte = (row * 512 + kk * 64 + qw * 16) ^ ((row & 7) << 4);
            a[m] = *reinterpret_cast<short8*>(&Xl[byte]);
        }
        #pragma unroll
        for (int nf = 0; nf < 4; ++nf) {
            int j = wv * 64 + nf * 16 + r15;
            int byte = (j * 64 + qw * 16) ^ ((j & 7) << 4);
            bbf[nf] = *reinterpret_cast<short8*>(&Wb[byte]);
        }
        #pragma unroll
        for (int m = 0; m < 4; ++m)
            #pragma unroll
            for (int nf = 0; nf < 4; ++nf)
                acc[m][nf] = __builtin_amdgcn_mfma_f32_16x16x32_bf16(a[m], bbf[nf], acc[m][nf], 0, 0, 0);
    };
    stageW(0, 0);
    int cur = 0;
    #pragma unroll
    for (int kk = 0; kk < 8; ++kk) {
        __syncthreads();
        if (kk < 7) stageW(cur ^ 1, kk + 1);
        computeK(cur, kk);
        cur ^= 1;
    }
    float ps[16];
    #pragma unroll
    for (int i = 0; i < 16; ++i) ps[i] = 0.f;
    #pragma unroll
    for (int m = 0; m < 4; ++m)
        #pragma unroll
        for (int nf = 0; nf < 4; ++nf) {
            int j = wv * 64 + nf * 16 + r15;
            #pragma unroll
            for (int r = 0; r < 4; ++r) {
                int brow = m * 16 + qw * 4 + r;
                int byte = (brow * 512 + j * 2) ^ ((brow & 7) << 4);
                float xv = bf2f(*reinterpret_cast<unsigned short*>(&Xl[byte]));
                ps[m * 4 + r] += acc[m][nf][r] * xv;
            }
        }
    #pragma unroll
    for (int off = 1; off <= 8; off <<= 1)
        #pragma unroll
        for (int i = 0; i < 16; ++i) ps[i] += __shfl_xor(ps[i], off, 64);
    __syncthreads();
    float* red = reinterpret_cast<float*>(Wl);
    if (r15 == 0) {
        #pragma unroll
        for (int m = 0; m < 4; ++m)
            #pragma unroll
            for (int r = 0; r < 4; ++r)
                red[wv * 64 + m * 16 + qw * 4 + r] = ps[m * 4 + r];
    }
    __syncthreads();
    if (tid < 64) {
        float s = red[tid] + red[64 + tid] + red[128 + tid] + red[192 + tid] + Wn[66048];
        H[(size_t)(b0 + tid) * DDIM + n] = s;
    }
}

__global__ __launch_bounds__(256) void out_kernel(
    const float* __restrict__ H, const float* __restrict__ w_out,
    const float* __restrict__ b_out, float* __restrict__ out)
{
    int b = blockIdx.x * 4 + (threadIdx.x >> 6);
    int lane = threadIdx.x & 63;
    const float* h = H + (size_t)b * 256;
    float s = 0.f;
    #pragma unroll
    for (int c = 0; c < 4; ++c) s += h[lane + c * 64] * w_out[lane + c * 64];
    #pragma unroll
    for (int off = 1; off < 64; off <<= 1) s += __shfl_xor(s, off, 64);
    if (lane == 0) out[b] = s + b_out[0];
}

extern "C" void kernel_launch(void* const* d_in, const int* in_sizes, int n_in,
                              void* d_out, int out_size, void* d_ws, size_t ws_size,
                              hipStream_t stream) {
    const float* x    = (const float*)d_in[0];
    const float* W1   = (const float*)d_in[1];
    const float* W2   = (const float*)d_in[2];
    const float* W3   = (const float*)d_in[3];
    const float* wout = (const float*)d_in[4];
    const float* bout = (const float*)d_in[5];
    float* out = (float*)d_out;

    const size_t WT_BYTES = (size_t)256 * 256 * 256 * 2;   // 33.55 MB
    const size_t XB_BYTES = (size_t)2048 * 256 * 2;        // 1 MB
    const size_t XE_BYTES = (size_t)2048 * 256 * 2;        // 1 MB
    const size_t HT_BYTES = (size_t)256 * 2048 * 2;        // 1 MB (bf16, transposed)
    const size_t need = WT_BYTES + XB_BYTES + XE_BYTES + 2 * HT_BYTES;  // 37.75 MB

    dim3 blk(256, 1, 1);

    if (ws_size >= need) {
        unsigned short* Wt2 = (unsigned short*)d_ws;
        unsigned short* Xbf = (unsigned short*)((char*)d_ws + WT_BYTES);
        unsigned short* Xe  = (unsigned short*)((char*)d_ws + WT_BYTES + XB_BYTES);
        unsigned short* Ht1 = (unsigned short*)((char*)d_ws + WT_BYTES + XB_BYTES + XE_BYTES);
        unsigned short* Ht2 = Ht1 + 256 * 2048;

        const float* Ws[3] = {W1, W2, W3};
        unsigned short* Hout[3] = {Ht1, Ht2, Ht1};

        dim3 wgrid(10, 256), lgrid(32, 256), xgrid(16);
        for (int L = 0; L < 3; ++L) {
            if (L == 0) conv_x_rm_kernel<<<xgrid, blk, 0, stream>>>(x, Xbf, Xe);
            else        conv_x_tr_kernel<<<xgrid, blk, 0, stream>>>(Hout[L - 1], Xbf, Xe);
            conv_w2_kernel<<<wgrid, blk, 0, stream>>>(Ws[L], Wt2);
            pn4_kernel<<<lgrid, blk, 0, stream>>>(Xbf, Xe, Wt2, Ws[L], Hout[L]);
        }
        out_tr_kernel<<<xgrid, blk, 0, stream>>>(Ht1, wout, bout, out);
    } else {
        float* h1 = (float*)d_ws;
        float* h2 = h1 + 2048 * 256;
        dim3 grid(32, 256);
        pn_layer_kernel<<<grid, blk, 0, stream>>>(x,  W1, h1);
        pn_layer_kernel<<<grid, blk, 0, stream>>>(h1, W2, h2);
        pn_layer_kernel<<<grid, blk, 0, stream>>>(h2, W3, h1);
        out_kernel<<<512, blk, 0, stream>>>(h1, wout, bout, out);
    }
}